// Round 4
// baseline (106.575 us; speedup 1.0000x reference)
//
#include <hip/hip_runtime.h>

// RBF: out[b,l] = exp(-(1/256) * max(||x_b||^2 + ||l_l||^2 - 2 x_b·l_l, 0))
// B=8192, L=2048, D=256. bf16 MFMA GEMM + fused epilogue.
// R1: counted-vmcnt double-buffer pipeline (kept, now vmcnt(4)).
// R2: XOR-swizzled LDS, both-sides involution (kept, re-derived for BK=32).
// R3: swapped MFMA operands -> row-major per-lane D -> f32x4 stores (kept).
// R4: BK=32 -> LDS 64->32 KB + __launch_bounds__(256,4): ~4 blocks/CU all
//     co-resident (was 2) for cross-block overlap of stage/compute/epilogue
//     tails; nontemporal output stores (stop evicting L2-resident A/B).

typedef __bf16 bf16x8 __attribute__((ext_vector_type(8)));
typedef float  f32x4  __attribute__((ext_vector_type(4)));

#define B_ROWS 8192
#define L_ROWS 2048
#define K_DIM  256

#define GLD_LDS(g, l) __builtin_amdgcn_global_load_lds(                      \
    (const __attribute__((address_space(1))) void*)(g),                      \
    (__attribute__((address_space(3))) void*)(l), 16, 0, 0)

__device__ __forceinline__ unsigned short f32_to_bf16_rne(float f) {
    union { float f; unsigned int u; } v; v.f = f;
    unsigned int u = v.u;
    unsigned int r = (u + 0x7fffu + ((u >> 16) & 1u)) >> 16;
    return (unsigned short)r;
}

// One wave per 256-float row: convert to bf16 (RNE) + fp32 squared-norm.
// Fused: first B_ROWS waves handle x, remaining L_ROWS waves handle landmarks.
__global__ __launch_bounds__(256) void cvt_rows_kernel(
    const float* __restrict__ x, const float* __restrict__ lm,
    unsigned short* __restrict__ xb, unsigned short* __restrict__ lb,
    float* __restrict__ x2, float* __restrict__ l2)
{
    const int lane = threadIdx.x & 63;
    const int gw   = blockIdx.x * 4 + (threadIdx.x >> 6);
    const float* in; unsigned short* outb; float* sq; int row;
    if (gw < B_ROWS) { in = x;  outb = xb; sq = x2; row = gw; }           // wave-uniform branch
    else             { in = lm; outb = lb; sq = l2; row = gw - B_ROWS; }
    const float4 v = ((const float4*)(in + (size_t)row * K_DIM))[lane];
    ushort4 o;
    o.x = f32_to_bf16_rne(v.x);
    o.y = f32_to_bf16_rne(v.y);
    o.z = f32_to_bf16_rne(v.z);
    o.w = f32_to_bf16_rne(v.w);
    ((ushort4*)(outb + (size_t)row * K_DIM))[lane] = o;
    float s = v.x*v.x + v.y*v.y + v.z*v.z + v.w*v.w;
    #pragma unroll
    for (int off = 32; off > 0; off >>= 1) s += __shfl_down(s, off, 64);
    if (lane == 0) sq[row] = s;
}

// 128x128 tile GEMM, NT layout (A [M,K] row-major, B [N,K] row-major),
// 4 waves in 2x2, each wave 64x64 via 4x4 of 16x16x32 bf16 MFMA. BK=32.
// LDS: [128 rows][32 bf16] per tile (64 B rows, 4x 16 B granules/row).
// Swizzle: LDS[row][g] = global[row][g ^ ((row>>1)&3)] — realized with a
// linear global_load_lds dest + pre-swizzled per-lane global source
// (rule #21); reads apply the same XOR. Read bank distribution: 8 lanes
// per 4-bank group = exact b128 bandwidth floor, conflict-free.
__global__ __launch_bounds__(256, 4) void rbf_gemm_kernel(
    const unsigned short* __restrict__ A,   // bf16 bits [8192][256]
    const unsigned short* __restrict__ Bm,  // bf16 bits [2048][256]
    const float* __restrict__ x2,
    const float* __restrict__ l2,
    float* __restrict__ out)                // [8192][2048]
{
    __shared__ unsigned short As[2][128 * 32];  // 2 x 8 KB
    __shared__ unsigned short Bs[2][128 * 32];  // 2 x 8 KB  -> 32 KB total

    const int tid  = threadIdx.x;
    const int wave = tid >> 6;
    const int lane = tid & 63;
    const int wm = wave >> 1, wn = wave & 1;
    const int bm = blockIdx.x, bn = blockIdx.y;

    f32x4 acc[4][4];
    #pragma unroll
    for (int i = 0; i < 4; ++i)
        #pragma unroll
        for (int j = 0; j < 4; ++j)
            acc[i][j] = (f32x4){0.f, 0.f, 0.f, 0.f};

    // Staging: lane l writes LDS base + 16*l (HW rule) == row l>>2 of the
    // 16-row group, granule l&3. Swizzle key for that row is (l>>3)&3
    // (group base is a multiple of 16 so it contributes 0 mod 4), so the
    // source granule is (l&3) ^ ((l>>3)&3).
    const int ldrow = lane >> 2;                               // 0..15
    const int ldcol = ((lane & 3) ^ ((lane >> 3) & 3)) * 8;    // swizzled src granule

    const unsigned short* Ab = A  + (size_t)(bm * 128) * K_DIM;
    const unsigned short* Bb = Bm + (size_t)(bn * 128) * K_DIM;

    // 4 global_load_lds per wave per stage (2 its x 2 arrays).
#define STAGE(buf, k0)                                                        \
    _Pragma("unroll")                                                         \
    for (int it = 0; it < 2; ++it) {                                          \
        const int r = wave * 32 + it * 16;                                    \
        GLD_LDS(Ab + (r + ldrow) * K_DIM + (k0) + ldcol, &As[buf][r * 32]);   \
        GLD_LDS(Bb + (r + ldrow) * K_DIM + (k0) + ldcol, &Bs[buf][r * 32]);   \
    }

    STAGE(0, 0);

    // Fragment read: granule q = lane>>4, row key = ((lane&15)>>1)&3
    // == (lane>>1)&3; tt*16/wm*64 contribute 0 mod 4 to the key.
    const int osw = ((lane >> 4) ^ ((lane >> 1) & 3)) * 8;     // elems

    #pragma unroll
    for (int t = 0; t < 8; ++t) {       // K_DIM/32 = 8 K-steps
        const int cur = t & 1;
        if (t < 7) { STAGE(cur ^ 1, (t + 1) * 32); }
        // Counted wait: the 4 newest (next-tile) loads stay in flight.
        if (t < 7) asm volatile("s_waitcnt vmcnt(4)" ::: "memory");
        else       asm volatile("s_waitcnt vmcnt(0)" ::: "memory");
        asm volatile("s_barrier" ::: "memory");   // all waves' stage(t) done

        bf16x8 af[4], bfr[4];
        #pragma unroll
        for (int tt = 0; tt < 4; ++tt) {
            af[tt]  = *(const bf16x8*)&As[cur][(wm*64 + tt*16 + (lane & 15)) * 32 + osw];
            bfr[tt] = *(const bf16x8*)&Bs[cur][(wn*64 + tt*16 + (lane & 15)) * 32 + osw];
        }
        // Swapped operands: D fragment lands transposed -> per-lane row-major
        // (m = lane&15, n = (lane>>4)*4 + reg) -> f32x4 stores in epilogue.
        #pragma unroll
        for (int mt = 0; mt < 4; ++mt)
            #pragma unroll
            for (int nt = 0; nt < 4; ++nt)
                acc[mt][nt] = __builtin_amdgcn_mfma_f32_16x16x32_bf16(
                    bfr[nt], af[mt], acc[mt][nt], 0, 0, 0);

        // Protect buf[cur] before t+1's STAGE overwrites it (targets cur^1
        // at t+1... which is buf[cur] at t+2; barrier needed each step).
        if (t < 7) asm volatile("s_barrier" ::: "memory");
    }
#undef STAGE

    // Epilogue (transposed D): per lane, row = ...+(lane&15) fixed per mt,
    // cols = ...+(lane>>4)*4 + {0..3} consecutive -> dwordx4 nt stores.
    const float gamma = 1.0f / 256.0f;
    const int row0 = bm * 128 + wm * 64 + (lane & 15);
    const int col0 = bn * 128 + wn * 64 + (lane >> 4) * 4;

    float xv[4];
    #pragma unroll
    for (int mt = 0; mt < 4; ++mt) xv[mt] = x2[row0 + mt * 16];
    f32x4 lv[4];
    #pragma unroll
    for (int nt = 0; nt < 4; ++nt) lv[nt] = *(const f32x4*)&l2[col0 + nt * 16];

    #pragma unroll
    for (int mt = 0; mt < 4; ++mt) {
        const size_t rb = (size_t)(row0 + mt * 16) * L_ROWS;
        #pragma unroll
        for (int nt = 0; nt < 4; ++nt) {
            f32x4 v;
            #pragma unroll
            for (int r = 0; r < 4; ++r) {
                float d2 = fmaxf(xv[mt] + lv[nt][r] - 2.0f * acc[mt][nt][r], 0.0f);
                v[r] = __expf(-gamma * d2);
            }
            __builtin_nontemporal_store(v, (f32x4*)&out[rb + col0 + nt * 16]);
        }
    }
}

extern "C" void kernel_launch(void* const* d_in, const int* in_sizes, int n_in,
                              void* d_out, int out_size, void* d_ws, size_t ws_size,
                              hipStream_t stream) {
    const float* x  = (const float*)d_in[0];   // [8192, 256]
    const float* lm = (const float*)d_in[1];   // [2048, 256]
    float* out = (float*)d_out;

    char* ws = (char*)d_ws;
    unsigned short* xb = (unsigned short*)ws;                               // 4 MB
    unsigned short* lb = (unsigned short*)(ws + (size_t)B_ROWS*K_DIM*2);    // 1 MB
    float* x2 = (float*)(ws + (size_t)B_ROWS*K_DIM*2 + (size_t)L_ROWS*K_DIM*2);
    float* l2 = x2 + B_ROWS;

    cvt_rows_kernel<<<(B_ROWS + L_ROWS)/4, 256, 0, stream>>>(x, lm, xb, lb, x2, l2);
    rbf_gemm_kernel<<<dim3(B_ROWS/128, L_ROWS/128), 256, 0, stream>>>(xb, lb, x2, l2, out);
}

// Round 5
// 98.314 us; speedup vs baseline: 1.0840x; 1.0840x over previous
//
#include <hip/hip_runtime.h>

// RBF: out[b,l] = exp(-(1/256) * max(||x_b||^2 + ||l_l||^2 - 2 x_b·l_l, 0))
// B=8192, L=2048, D=256. bf16 MFMA GEMM + fused epilogue.
// R1: counted-vmcnt double-buffer pipeline (kept).
// R2: XOR-swizzled LDS, both-sides involution (kept).
// R3: swapped MFMA operands -> row-major per-lane D -> f32x4 stores (kept).
// R4: REVERTED (BK=32 + launch_bounds(256,4) caused VGPR spills, +16 us).
// R5: 256x256 tile, 8 waves (2Mx4N), BK=64, 128 KB LDS, grid=256 blocks
//     = exactly 1 block/CU (no generation tails); bijective XCD swizzle so
//     each XCD owns one bn-column (B panel L2-resident, A fits 4 MB L2);
//     panel fetch 128->64 MB. VGPR: acc 128 + frags 48 -> cap 256 via
//     __launch_bounds__(512,2), no spills.

typedef __bf16 bf16x8 __attribute__((ext_vector_type(8)));
typedef float  f32x4  __attribute__((ext_vector_type(4)));

#define B_ROWS 8192
#define L_ROWS 2048
#define K_DIM  256

#define GLD_LDS(g, l) __builtin_amdgcn_global_load_lds(                      \
    (const __attribute__((address_space(1))) void*)(g),                      \
    (__attribute__((address_space(3))) void*)(l), 16, 0, 0)

__device__ __forceinline__ unsigned short f32_to_bf16_rne(float f) {
    union { float f; unsigned int u; } v; v.f = f;
    unsigned int u = v.u;
    unsigned int r = (u + 0x7fffu + ((u >> 16) & 1u)) >> 16;
    return (unsigned short)r;
}

// One wave per 256-float row: convert to bf16 (RNE) + fp32 squared-norm.
// Fused: first B_ROWS waves handle x, remaining L_ROWS waves handle landmarks.
__global__ __launch_bounds__(256) void cvt_rows_kernel(
    const float* __restrict__ x, const float* __restrict__ lm,
    unsigned short* __restrict__ xb, unsigned short* __restrict__ lb,
    float* __restrict__ x2, float* __restrict__ l2)
{
    const int lane = threadIdx.x & 63;
    const int gw   = blockIdx.x * 4 + (threadIdx.x >> 6);
    const float* in; unsigned short* outb; float* sq; int row;
    if (gw < B_ROWS) { in = x;  outb = xb; sq = x2; row = gw; }           // wave-uniform branch
    else             { in = lm; outb = lb; sq = l2; row = gw - B_ROWS; }
    const float4 v = ((const float4*)(in + (size_t)row * K_DIM))[lane];
    ushort4 o;
    o.x = f32_to_bf16_rne(v.x);
    o.y = f32_to_bf16_rne(v.y);
    o.z = f32_to_bf16_rne(v.z);
    o.w = f32_to_bf16_rne(v.w);
    ((ushort4*)(outb + (size_t)row * K_DIM))[lane] = o;
    float s = v.x*v.x + v.y*v.y + v.z*v.z + v.w*v.w;
    #pragma unroll
    for (int off = 32; off > 0; off >>= 1) s += __shfl_down(s, off, 64);
    if (lane == 0) sq[row] = s;
}

// 256x256 tile GEMM, NT layout (A [M,K] row-major, B [N,K] row-major).
// 8 waves in 2(M)x4(N); each wave 128x64 via 8x4 of 16x16x32 bf16 MFMA.
// BK=64, double-buffered (128 KB LDS). Counted vmcnt(8).
// LDS rows are 64 bf16 = 128 B = 8 granules of 16 B; swizzle
// LDS[row][g] = global[row][g ^ (row&7)], realized with linear
// global_load_lds dest + pre-swizzled global source; reads XOR the same key.
__global__ __launch_bounds__(512, 2) void rbf_gemm_kernel(
    const unsigned short* __restrict__ A,   // bf16 bits [8192][256]
    const unsigned short* __restrict__ Bm,  // bf16 bits [2048][256]
    const float* __restrict__ x2,
    const float* __restrict__ l2,
    float* __restrict__ out)                // [8192][2048]
{
    __shared__ unsigned short As[2][256 * 64];  // 2 x 32 KB
    __shared__ unsigned short Bs[2][256 * 64];  // 2 x 32 KB -> 128 KB total

    const int tid  = threadIdx.x;
    const int wave = tid >> 6;
    const int lane = tid & 63;
    const int wm = wave >> 2;          // 0..1  (M)
    const int wn = wave & 3;           // 0..3  (N)

    // Bijective XCD swizzle (256 blocks, 256%8==0): XCD x gets wg in
    // [x*32, x*32+32) -> all same bn (one B panel per XCD L2).
    const int bid = blockIdx.x;
    const int wg  = (bid & 7) * 32 + (bid >> 3);
    const int bm  = wg & 31;           // 0..31
    const int bn  = wg >> 5;           // 0..7

    f32x4 acc[8][4];
    #pragma unroll
    for (int i = 0; i < 8; ++i)
        #pragma unroll
        for (int j = 0; j < 4; ++j)
            acc[i][j] = (f32x4){0.f, 0.f, 0.f, 0.f};

    // Staging: lane l writes LDS base + 16*l (HW rule) == row l>>3 of the
    // 8-row group, granule l&7. Row groups are 8-aligned so the swizzle key
    // is l>>3; source granule = (l&7) ^ (l>>3).
    const int ldrow = lane >> 3;                         // 0..7
    const int ldcol = (((lane & 7) ^ ldrow) * 8);        // swizzled src granule

    const unsigned short* Ab = A  + (size_t)(bm * 256) * K_DIM;
    const unsigned short* Bb = Bm + (size_t)(bn * 256) * K_DIM;

    // 8 global_load_lds per wave per stage (4 it x 2 arrays), 256 rows total.
#define STAGE(buf, k0)                                                       \
    _Pragma("unroll")                                                        \
    for (int it = 0; it < 4; ++it) {                                         \
        const int r = wave * 32 + it * 8;                                    \
        GLD_LDS(Ab + (r + ldrow) * K_DIM + (k0) + ldcol, &As[buf][r * 64]);  \
        GLD_LDS(Bb + (r + ldrow) * K_DIM + (k0) + ldcol, &Bs[buf][r * 64]);  \
    }

    STAGE(0, 0);

    const int xr = (lane & 7) << 4;    // read-side XOR (bytes) == (row&7)<<4

    #pragma unroll
    for (int t = 0; t < 4; ++t) {       // K_DIM/64 = 4 K-steps
        const int cur = t & 1;
        if (t < 3) { STAGE(cur ^ 1, (t + 1) * 64); }
        // Counted wait: the 8 newest (next-tile) loads stay in flight.
        if (t < 3) asm volatile("s_waitcnt vmcnt(8)" ::: "memory");
        else       asm volatile("s_waitcnt vmcnt(0)" ::: "memory");
        asm volatile("s_barrier" ::: "memory");   // all waves' stage(t) done

        #pragma unroll
        for (int kk = 0; kk < 64; kk += 32) {
            // Within-row byte offset before swizzle: kk*2 + quad*16.
            const int osw = ((kk * 2 + (lane >> 4) * 16) ^ xr) >> 1;  // elems
            bf16x8 af[8], bfr[4];
            #pragma unroll
            for (int nt = 0; nt < 4; ++nt)
                bfr[nt] = *(const bf16x8*)&Bs[cur][(wn*64 + nt*16 + (lane & 15)) * 64 + osw];
            #pragma unroll
            for (int mt = 0; mt < 8; ++mt)
                af[mt]  = *(const bf16x8*)&As[cur][(wm*128 + mt*16 + (lane & 15)) * 64 + osw];
            // Swapped operands: per-lane row-major D fragment
            // (m = lane&15, n = (lane>>4)*4 + reg) -> f32x4 stores.
            #pragma unroll
            for (int mt = 0; mt < 8; ++mt)
                #pragma unroll
                for (int nt = 0; nt < 4; ++nt)
                    acc[mt][nt] = __builtin_amdgcn_mfma_f32_16x16x32_bf16(
                        bfr[nt], af[mt], acc[mt][nt], 0, 0, 0);
        }
        // Protect buf[cur] before t+1's STAGE overwrites it.
        if (t < 3) asm volatile("s_barrier" ::: "memory");
    }
#undef STAGE

    // Epilogue (transposed D): per lane, row = ...+(lane&15) fixed per mt,
    // cols = ...+(lane>>4)*4 + {0..3} consecutive -> dwordx4 nt stores.
    const float gamma = 1.0f / 256.0f;
    const int row0 = bm * 256 + wm * 128 + (lane & 15);
    const int col0 = bn * 256 + wn * 64 + (lane >> 4) * 4;

    f32x4 lv[4];
    #pragma unroll
    for (int nt = 0; nt < 4; ++nt) lv[nt] = *(const f32x4*)&l2[col0 + nt * 16];

    #pragma unroll
    for (int mt = 0; mt < 8; ++mt) {
        const int row = row0 + mt * 16;
        const float xv = x2[row];
        const size_t rb = (size_t)row * L_ROWS;
        #pragma unroll
        for (int nt = 0; nt < 4; ++nt) {
            f32x4 v;
            #pragma unroll
            for (int r = 0; r < 4; ++r) {
                float d2 = fmaxf(xv + lv[nt][r] - 2.0f * acc[mt][nt][r], 0.0f);
                v[r] = __expf(-gamma * d2);
            }
            __builtin_nontemporal_store(v, (f32x4*)&out[rb + col0 + nt * 16]);
        }
    }
}

extern "C" void kernel_launch(void* const* d_in, const int* in_sizes, int n_in,
                              void* d_out, int out_size, void* d_ws, size_t ws_size,
                              hipStream_t stream) {
    const float* x  = (const float*)d_in[0];   // [8192, 256]
    const float* lm = (const float*)d_in[1];   // [2048, 256]
    float* out = (float*)d_out;

    char* ws = (char*)d_ws;
    unsigned short* xb = (unsigned short*)ws;                               // 4 MB
    unsigned short* lb = (unsigned short*)(ws + (size_t)B_ROWS*K_DIM*2);    // 1 MB
    float* x2 = (float*)(ws + (size_t)B_ROWS*K_DIM*2 + (size_t)L_ROWS*K_DIM*2);
    float* l2 = x2 + B_ROWS;

    cvt_rows_kernel<<<(B_ROWS + L_ROWS)/4, 256, 0, stream>>>(x, lm, xb, lb, x2, l2);
    rbf_gemm_kernel<<<256, 512, 0, stream>>>(xb, lb, x2, l2, out);
}